// Round 5
// baseline (412.980 us; speedup 1.0000x reference)
//
#include <hip/hip_runtime.h>
#include <hip/hip_fp16.h>

#define BB 4
#define HH 192
#define WW 640
#define CC 32
#define SS 32
#define PXB 128           // pixels per block = two waves; 640 % 128 == 0
#define NT 128            // threads per block
#define MAXW 144          // staged window (source px); covers alpha <= ~1.11
#define PLANE (MAXW + 1)  // 145; 145 mod 8 = 1 rotates bank-groups per plane

typedef _Float16 half2n __attribute__((ext_vector_type(2)));

#if defined(__has_builtin)
#if __has_builtin(__builtin_amdgcn_fdot2)
#define HAS_FDOT2 1
#endif
#endif

static __device__ __forceinline__ float fdot2_acc(__half2 a, __half2 b, float acc) {
#ifdef HAS_FDOT2
    return __builtin_amdgcn_fdot2(__builtin_bit_cast(half2n, a),
                                  __builtin_bit_cast(half2n, b), acc, false);
#else
    const float2 af = __half22float2(a);
    const float2 bf = __half22float2(b);
    return acc + af.x * bf.x + af.y * bf.y;
#endif
}

static __device__ __forceinline__ unsigned pk2(float w) {
    // half2(w, w) as a packed uint
    return (unsigned)__builtin_bit_cast(unsigned short, __float2half_rn(w)) * 0x10001u;
}

// x (fp32, 63MB) -> fp16 copy in workspace (31.5MB). Re-run every call.
__global__ __launch_bounds__(256) void convert_x_kernel(const float* __restrict__ x,
                                                        __half* __restrict__ xh) {
    const size_t i = ((size_t)blockIdx.x * 256 + threadIdx.x) * 8;
    const float4 f0 = *(const float4*)(x + i);
    const float4 f1 = *(const float4*)(x + i + 4);
    uint4 u;
    u.x = __builtin_bit_cast(unsigned, __floats2half2_rn(f0.x, f0.y));
    u.y = __builtin_bit_cast(unsigned, __floats2half2_rn(f0.z, f0.w));
    u.z = __builtin_bit_cast(unsigned, __floats2half2_rn(f1.x, f1.y));
    u.w = __builtin_bit_cast(unsigned, __floats2half2_rn(f1.z, f1.w));
    *(uint4*)(xh + i) = u;
}

// R12: R11's lane-per-pixel structure, occupancy fixed.
//  R11 post-mortem: VALUBusy 33% (per-pixel math win confirmed) but
//  Occupancy 37.6% -> latency-bound (64-thread blocks, ~3 waves/SIMD).
//  Single change: PXB 64->128, block = 2 waves, lane-per-pixel across both.
//  LDS stays ~10.3KB/block but now carries 2 waves -> 15 blocks/CU =
//  30 waves/CU (~94%), giving 7.5 independent step-chains per SIMD to hide
//  the global->LDS->consume serial latency R11 exposed. Staging window
//  (~alpha*127+2 px) also amortizes slightly better per output pixel.
//  Cross-wave staging uses R9's proven 2-barrier-per-step discipline.
__global__ __launch_bounds__(NT, 7) void corr_kernel(
    const __half* __restrict__ xh, const float* __restrict__ y,
    const float* __restrict__ origin, const float* __restrict__ focal,
    const float* __restrict__ T12, float* __restrict__ out)
{
    // sU[s] = { alpha, dkx, xlo, width4 }   sV[s] = { r0byte, r1byte, wy0pk, wy1pk }
    __shared__ uint4 sU[SS];
    __shared__ uint4 sV[SS];
    __shared__ uint4 comb[4][PLANE];   // 9,280 B

    const int tid = threadIdx.x;

    const int p0 = blockIdx.x * PXB;
    const int w0 = p0 % WW;
    const int h  = (p0 / WW) % HH;
    const int b  = p0 / (WW * HH);

    // ---- per-step uniforms (threads 0..31, one step each; R9-proven) ----
    if (tid < SS) {
        const float tz = T12[b * 3 + 2];
        const float kx = tz * origin[b * 2 + 0] + focal[b * 2 + 0] * T12[b * 3 + 0];
        const float ky = tz * origin[b * 2 + 1] + focal[b * 2 + 1] * T12[b * 3 + 1];
        const float sf = (float)tid;
        // D = s/(1+s*tz); s=0 -> D=0 automatically (matches reference).
        const float D = sf * __builtin_amdgcn_rcpf(1.0f + sf * tz);
        const float alpha = 1.0f - D * tz;
        const float dkx = D * kx;
        const float dky = D * ky;

        const float syv = alpha * (float)h + dky;
        const float y0f = floorf(syv);
        const float fy  = syv - y0f;
        const int   y0  = (int)y0f;
        const int   y1  = y0 + 1;
        const float wy0 = (y0 >= 0 && y0 < HH) ? (1.0f - fy) : 0.0f;
        const float wy1 = (y1 >= 0 && y1 < HH) ? fy : 0.0f;
        const int   cy0 = min(max(y0, 0), HH - 1);
        const int   cy1 = min(max(y1, 0), HH - 1);

        // source x window for this block (sx is linear in pixel index)
        const float sxa = alpha * (float)w0 + dkx;
        const float sxb = alpha * (float)(w0 + PXB - 1) + dkx;
        const int xlo = (int)floorf(fminf(sxa, sxb));
        const int xhi = (int)floorf(fmaxf(sxa, sxb)) + 1;
        const int width4 = (xhi - xlo + 1) * 4;   // 16B chunks to stage

        uint4 U, V;
        U.x = __builtin_bit_cast(unsigned, alpha);
        U.y = __builtin_bit_cast(unsigned, dkx);
        U.z = (unsigned)xlo;
        U.w = (unsigned)width4;
        V.x = (unsigned)((cy0 * WW) << 6);   // row byte base in fp16 image
        V.y = (unsigned)((cy1 * WW) << 6);
        V.z = pk2(wy0);
        V.w = pk2(wy1);
        sU[tid] = U;
        sV[tid] = V;
    }

    const int pme = p0 + tid;     // lane-per-pixel across both waves
    // lane's 32 y channels as 16 half2 (coalesced: 128B/lane consecutive)
    __half2 yh[16];
    {
        const float4* yp = (const float4*)(y + (size_t)pme * CC);
#pragma unroll
        for (int q = 0; q < 8; ++q) {
            const float4 f = yp[q];
            yh[2 * q]     = __floats2half2_rn(f.x, f.y);
            yh[2 * q + 1] = __floats2half2_rn(f.z, f.w);
        }
    }

    const char* xbase = (const char*)(xh + (size_t)b * HH * WW * CC);
    const float pxf = (float)(w0 + tid);
    float* outp = out + (size_t)pme * SS;

    __syncthreads();   // uniforms table ready

#pragma unroll 1
    for (int g = 0; g < 4; ++g) {
        float res[8];
#pragma unroll
        for (int j = 0; j < 8; ++j) {
            const int s = g * 8 + j;
            const uint4 U = sU[s];                 // broadcast ds_read
            const uint4 V = sV[s];
            const float alpha  = __builtin_bit_cast(float, U.x);
            const float dkx    = __builtin_bit_cast(float, U.y);
            const int   xlo    = (int)U.z;
            const int   width4 = (int)U.w;
            const bool  fits   = (width4 <= MAXW * 4);   // block-uniform

            // ---- per-lane x interpolation params ----
            const float sx  = alpha * pxf + dkx;
            const float x0f = floorf(sx);
            const float fx  = sx - x0f;
            const int   x0  = (int)x0f;
            const int   x1  = x0 + 1;
            const float wx0f = (x0 >= 0 && x0 < WW) ? (1.0f - fx) : 0.0f;
            const float wx1f = (x1 >= 0 && x1 < WW) ? fx : 0.0f;
            const __half2 wx0 = __builtin_bit_cast(__half2, pk2(wx0f));
            const __half2 wx1 = __builtin_bit_cast(__half2, pk2(wx1f));
            const int cx0 = min(max(x0, 0), WW - 1);
            const int cx1 = min(max(x1, 0), WW - 1);

            // ---- stage: comb = wy0*row0 + wy1*row1, SoA planes ----
            if (fits) {
                const __half2 wy0h = __builtin_bit_cast(__half2, V.z);
                const __half2 wy1h = __builtin_bit_cast(__half2, V.w);
                for (int c = tid; c < width4; c += NT) {
                    const int cpx = min(max(xlo + (c >> 2), 0), WW - 1);
                    const unsigned po = (unsigned)((cpx << 6) + ((c & 3) << 4));
                    const uint4 a  = *(const uint4*)(xbase + (size_t)(V.x + po));
                    const uint4 bq = *(const uint4*)(xbase + (size_t)(V.y + po));
                    uint4 o;
#pragma unroll
                    for (int i = 0; i < 4; ++i) {
                        __half2 r = __hmul2(__builtin_bit_cast(__half2, (&a.x)[i]), wy0h);
                        r = __hfma2(__builtin_bit_cast(__half2, (&bq.x)[i]), wy1h, r);
                        (&o.x)[i] = __builtin_bit_cast(unsigned, r);
                    }
                    comb[c & 3][c >> 2] = o;
                }
            }
            __syncthreads();   // stage(s) visible to both waves before consume

            float acc = 0.0f;
            if (fits) {
                const int wlim = (width4 >> 2) - 1;
                const int l0 = min(max(cx0 - xlo, 0), wlim);
                const int l1 = min(max(cx1 - xlo, 0), wlim);
                const uint4* b0 = &comb[0][l0];
                const uint4* b1 = &comb[0][l1];
                uint4 A[4], Bq[4];
#pragma unroll
                for (int i = 0; i < 4; ++i) {
                    A[i]  = b0[i * PLANE];          // imm offsets i*2320
                    Bq[i] = b1[i * PLANE];
                }
#pragma unroll
                for (int i = 0; i < 4; ++i) {
#pragma unroll
                    for (int w = 0; w < 4; ++w) {
                        __half2 v = __hmul2(__builtin_bit_cast(__half2, (&A[i].x)[w]), wx0);
                        v = __hfma2(__builtin_bit_cast(__half2, (&Bq[i].x)[w]), wx1, v);
                        acc = fdot2_acc(v, yh[i * 4 + w], acc);
                    }
                }
            } else {
                // rare fallback: direct 4-corner gather (window too wide for LDS)
                const __half2 wy0h = __builtin_bit_cast(__half2, V.z);
                const __half2 wy1h = __builtin_bit_cast(__half2, V.w);
                const uint4* r0p0 = (const uint4*)(xbase + (size_t)(V.x + ((unsigned)cx0 << 6)));
                const uint4* r0p1 = (const uint4*)(xbase + (size_t)(V.x + ((unsigned)cx1 << 6)));
                const uint4* r1p0 = (const uint4*)(xbase + (size_t)(V.y + ((unsigned)cx0 << 6)));
                const uint4* r1p1 = (const uint4*)(xbase + (size_t)(V.y + ((unsigned)cx1 << 6)));
#pragma unroll
                for (int i = 0; i < 4; ++i) {
                    const uint4 a  = r0p0[i];
                    const uint4 bq = r0p1[i];
                    const uint4 c2 = r1p0[i];
                    const uint4 d  = r1p1[i];
#pragma unroll
                    for (int w = 0; w < 4; ++w) {
                        __half2 top = __hmul2(__builtin_bit_cast(__half2, (&a.x)[w]), wx0);
                        top = __hfma2(__builtin_bit_cast(__half2, (&bq.x)[w]), wx1, top);
                        __half2 bot = __hmul2(__builtin_bit_cast(__half2, (&c2.x)[w]), wx0);
                        bot = __hfma2(__builtin_bit_cast(__half2, (&d.x)[w]), wx1, bot);
                        __half2 v = __hmul2(top, wy0h);
                        v = __hfma2(bot, wy1h, v);
                        acc = fdot2_acc(v, yh[i * 4 + w], acc);
                    }
                }
            }
            __syncthreads();   // consume done before next step's stage (WAR)

            res[j] = acc * (1.0f / 32.0f);
        }
        // 32B sector-aligned store per 8-step group; no transpose needed.
        *(float4*)(outp + g * 8)     = make_float4(res[0], res[1], res[2], res[3]);
        *(float4*)(outp + g * 8 + 4) = make_float4(res[4], res[5], res[6], res[7]);
    }
}

extern "C" void kernel_launch(void* const* d_in, const int* in_sizes, int n_in,
                              void* d_out, int out_size, void* d_ws, size_t ws_size,
                              hipStream_t stream) {
    const float* x = (const float*)d_in[0];
    const float* y = (const float*)d_in[1];
    const float* origin = (const float*)d_in[2];
    const float* focal = (const float*)d_in[3];
    const float* T12 = (const float*)d_in[4];
    float* out = (float*)d_out;
    __half* xh = (__half*)d_ws;   // needs BB*HH*WW*CC*2 = 31.5 MB

    const int nelem = BB * HH * WW * CC;          // 15,728,640
    convert_x_kernel<<<nelem / (256 * 8), 256, 0, stream>>>(x, xh);

    const int npix = BB * HH * WW;                // 491,520
    corr_kernel<<<npix / PXB, NT, 0, stream>>>(xh, y, origin, focal, T12, out);
}

// Round 6
// 324.510 us; speedup vs baseline: 1.2726x; 1.2726x over previous
//
#include <hip/hip_runtime.h>
#include <hip/hip_fp16.h>

#define BB 4
#define HH 192
#define WW 640
#define CC 32
#define SS 32
#define PXB 64            // pixels per block = one wave; 640 % 64 == 0
#define NWG (BB * HH * WW / PXB)   // 7680 blocks; divisible by 8 (XCD swizzle)
#define MAXW 140          // tier-1 staged window bound (source px)
#define PLANE (MAXW + 1)  // 141
#define PW 5              // prefetch chunks per lane; tier-0 iff width4 <= PW*64 (80 px)

typedef _Float16 half2n __attribute__((ext_vector_type(2)));

#if defined(__has_builtin)
#if __has_builtin(__builtin_amdgcn_fdot2)
#define HAS_FDOT2 1
#endif
#endif

static __device__ __forceinline__ float fdot2_acc(__half2 a, __half2 b, float acc) {
#ifdef HAS_FDOT2
    return __builtin_amdgcn_fdot2(__builtin_bit_cast(half2n, a),
                                  __builtin_bit_cast(half2n, b), acc, false);
#else
    const float2 af = __half22float2(a);
    const float2 bf = __half22float2(b);
    return acc + af.x * bf.x + af.y * bf.y;
#endif
}

static __device__ __forceinline__ unsigned pk2(float w) {
    // half2(w, w) as a packed uint
    return (unsigned)__builtin_bit_cast(unsigned short, __float2half_rn(w)) * 0x10001u;
}

// x (fp32, 63MB) -> fp16 copy in workspace (31.5MB). Re-run every call.
__global__ __launch_bounds__(256) void convert_x_kernel(const float* __restrict__ x,
                                                        __half* __restrict__ xh) {
    const size_t i = ((size_t)blockIdx.x * 256 + threadIdx.x) * 8;
    const float4 f0 = *(const float4*)(x + i);
    const float4 f1 = *(const float4*)(x + i + 4);
    uint4 u;
    u.x = __builtin_bit_cast(unsigned, __floats2half2_rn(f0.x, f0.y));
    u.y = __builtin_bit_cast(unsigned, __floats2half2_rn(f0.z, f0.w));
    u.z = __builtin_bit_cast(unsigned, __floats2half2_rn(f1.x, f1.y));
    u.w = __builtin_bit_cast(unsigned, __floats2half2_rn(f1.z, f1.w));
    *(uint4*)(xh + i) = u;
}

// R13: R11 structure (1-wave blocks, lane-per-pixel; reverted R12's 2-wave
// coupling which regressed) + two additions:
//  (1) T14 async-STAGE: at step s, ISSUE step s+1's staging loads into regs
//      (PW=5 fixed chunks/lane, clamped+masked), consume step s from LDS,
//      THEN combine+ds_write the regs and barrier. Load latency hides under
//      the consume VALU work instead of being serially exposed (R11:
//      VALU 33%, latency-bound). One barrier/step: write->consume RAW;
//      the consume(s)->write(s+1) WAR is safe because a single wave's DS
//      ops execute in order.
//  (2) XCD-aware bijective swizzle: HW round-robins blocks over 8 XCDs, so
//      blocks sharing a source row hit 8 different L2s (FETCH 296MB ~ 10x
//      the 31.5MB x image). Remap so each XCD gets a contiguous 960-block
//      range; row pairs then L2-hit, cutting HBM fetch AND load latency.
//  Tiers per step (wave-uniform, from width4): 0 = prefetch-staged (<=80px),
//  1 = serial-staged (<=MAXW px, R11 code), 2 = direct gather (R11 code).
__global__ __launch_bounds__(64, 4) void corr_kernel(
    const __half* __restrict__ xh, const float* __restrict__ y,
    const float* __restrict__ origin, const float* __restrict__ focal,
    const float* __restrict__ T12, float* __restrict__ out)
{
    // sU[s] = { alpha, dkx, xlo, width4 }   sV[s] = { r0byte, r1byte, wy0pk, wy1pk }
    __shared__ uint4 sU[SS];
    __shared__ uint4 sV[SS];
    __shared__ uint4 comb[4][PLANE];   // 9,024 B

    const int lane = threadIdx.x;
    // XCD swizzle: block bid0 runs the work of bid; XCD k (= bid0 & 7) covers
    // the contiguous range [k*960, (k+1)*960). Bijective since NWG % 8 == 0.
    const int bid = ((int)blockIdx.x & 7) * (NWG >> 3) + ((int)blockIdx.x >> 3);

    const int p0 = bid * PXB;
    const int w0 = p0 % WW;
    const int h  = (p0 / WW) % HH;
    const int b  = p0 / (WW * HH);

    // ---- per-step uniforms (lanes 0..31, one step each; R9/R11-proven) ----
    if (lane < SS) {
        const float tz = T12[b * 3 + 2];
        const float kx = tz * origin[b * 2 + 0] + focal[b * 2 + 0] * T12[b * 3 + 0];
        const float ky = tz * origin[b * 2 + 1] + focal[b * 2 + 1] * T12[b * 3 + 1];
        const float sf = (float)lane;
        // D = s/(1+s*tz); s=0 -> D=0 automatically (matches reference).
        const float D = sf * __builtin_amdgcn_rcpf(1.0f + sf * tz);
        const float alpha = 1.0f - D * tz;
        const float dkx = D * kx;
        const float dky = D * ky;

        const float syv = alpha * (float)h + dky;
        const float y0f = floorf(syv);
        const float fy  = syv - y0f;
        const int   y0  = (int)y0f;
        const int   y1  = y0 + 1;
        const float wy0 = (y0 >= 0 && y0 < HH) ? (1.0f - fy) : 0.0f;
        const float wy1 = (y1 >= 0 && y1 < HH) ? fy : 0.0f;
        const int   cy0 = min(max(y0, 0), HH - 1);
        const int   cy1 = min(max(y1, 0), HH - 1);

        const float sxa = alpha * (float)w0 + dkx;
        const float sxb = alpha * (float)(w0 + PXB - 1) + dkx;
        const int xlo = (int)floorf(fminf(sxa, sxb));
        const int xhi = (int)floorf(fmaxf(sxa, sxb)) + 1;
        const int width4 = (xhi - xlo + 1) * 4;   // 16B chunks to stage

        uint4 U, V;
        U.x = __builtin_bit_cast(unsigned, alpha);
        U.y = __builtin_bit_cast(unsigned, dkx);
        U.z = (unsigned)xlo;
        U.w = (unsigned)width4;
        V.x = (unsigned)((cy0 * WW) << 6);   // row byte base in fp16 image
        V.y = (unsigned)((cy1 * WW) << 6);
        V.z = pk2(wy0);
        V.w = pk2(wy1);
        sU[lane] = U;
        sV[lane] = V;
    }

    const int pme = p0 + lane;
    // lane's 32 y channels as 16 half2 (coalesced: 64 lanes x 128B consecutive)
    __half2 yh[16];
    {
        const float4* yp = (const float4*)(y + (size_t)pme * CC);
#pragma unroll
        for (int q = 0; q < 8; ++q) {
            const float4 f = yp[q];
            yh[2 * q]     = __floats2half2_rn(f.x, f.y);
            yh[2 * q + 1] = __floats2half2_rn(f.z, f.w);
        }
    }

    const char* xbase = (const char*)(xh + (size_t)b * HH * WW * CC);
    const float pxf = (float)(w0 + lane);
    float* outp = out + (size_t)pme * SS;

    __syncthreads();   // uniforms table ready

    // ---- prologue: stage step 0 (serially; tiers 0/1 both via the loop) ----
    uint4 U = sU[0];
    uint4 V = sV[0];
    {
        const int xlo    = (int)U.z;
        const int width4 = (int)U.w;
        if (width4 <= MAXW * 4) {
            const __half2 wy0h = __builtin_bit_cast(__half2, V.z);
            const __half2 wy1h = __builtin_bit_cast(__half2, V.w);
            for (int c = lane; c < width4; c += 64) {
                const int cpx = min(max(xlo + (c >> 2), 0), WW - 1);
                const unsigned po = (unsigned)((cpx << 6) + ((c & 3) << 4));
                const uint4 a  = *(const uint4*)(xbase + (size_t)(V.x + po));
                const uint4 bq = *(const uint4*)(xbase + (size_t)(V.y + po));
                uint4 o;
#pragma unroll
                for (int i = 0; i < 4; ++i) {
                    __half2 r = __hmul2(__builtin_bit_cast(__half2, (&a.x)[i]), wy0h);
                    r = __hfma2(__builtin_bit_cast(__half2, (&bq.x)[i]), wy1h, r);
                    (&o.x)[i] = __builtin_bit_cast(unsigned, r);
                }
                comb[c & 3][c >> 2] = o;
            }
            __syncthreads();   // stage(0) visible before consume(0)
        }
    }

#pragma unroll 1
    for (int g = 0; g < 4; ++g) {
        float res[8];
#pragma unroll
        for (int j = 0; j < 8; ++j) {
            const int s = g * 8 + j;
            const float alpha  = __builtin_bit_cast(float, U.x);
            const float dkx    = __builtin_bit_cast(float, U.y);
            const int   xlo    = (int)U.z;
            const int   width4 = (int)U.w;

            // ---- per-lane x interpolation params for step s ----
            const float sx  = alpha * pxf + dkx;
            const float x0f = floorf(sx);
            const float fx  = sx - x0f;
            const int   x0  = (int)x0f;
            const int   x1  = x0 + 1;
            const float wx0f = (x0 >= 0 && x0 < WW) ? (1.0f - fx) : 0.0f;
            const float wx1f = (x1 >= 0 && x1 < WW) ? fx : 0.0f;
            const __half2 wx0 = __builtin_bit_cast(__half2, pk2(wx0f));
            const __half2 wx1 = __builtin_bit_cast(__half2, pk2(wx1f));
            const int cx0 = min(max(x0, 0), WW - 1);
            const int cx1 = min(max(x1, 0), WW - 1);

            // ---- ISSUE: step s+1 staging loads into registers (tier 0) ----
            uint4 pa[PW], pb[PW];
            uint4 Un, Vn;
            int tn = 3, xlon = 0, width4n = 0;
            if (s + 1 < SS) {
                Un = sU[s + 1];
                Vn = sV[s + 1];
                xlon    = (int)Un.z;
                width4n = (int)Un.w;
                tn = (width4n <= PW * 64) ? 0 : ((width4n <= MAXW * 4) ? 1 : 2);
                if (tn == 0) {
#pragma unroll
                    for (int i = 0; i < PW; ++i) {
                        const int c  = lane + i * 64;
                        const int cc = min(c, width4n - 1);        // clamp (masked on store)
                        const int cpx = min(max(xlon + (cc >> 2), 0), WW - 1);
                        const unsigned po = (unsigned)((cpx << 6) + ((cc & 3) << 4));
                        pa[i] = *(const uint4*)(xbase + (size_t)(Vn.x + po));
                        pb[i] = *(const uint4*)(xbase + (size_t)(Vn.y + po));
                    }
                }
            }

            // ---- CONSUME step s (overlaps with the loads above) ----
            float acc = 0.0f;
            if (width4 <= MAXW * 4) {
                const int wlim = (width4 >> 2) - 1;
                const int l0 = min(max(cx0 - xlo, 0), wlim);
                const int l1 = min(max(cx1 - xlo, 0), wlim);
                const uint4* b0 = &comb[0][l0];
                const uint4* b1 = &comb[0][l1];
                uint4 A[4], Bq[4];
#pragma unroll
                for (int i = 0; i < 4; ++i) {
                    A[i]  = b0[i * PLANE];          // imm offsets i*2256
                    Bq[i] = b1[i * PLANE];
                }
#pragma unroll
                for (int i = 0; i < 4; ++i) {
#pragma unroll
                    for (int w = 0; w < 4; ++w) {
                        __half2 v = __hmul2(__builtin_bit_cast(__half2, (&A[i].x)[w]), wx0);
                        v = __hfma2(__builtin_bit_cast(__half2, (&Bq[i].x)[w]), wx1, v);
                        acc = fdot2_acc(v, yh[i * 4 + w], acc);
                    }
                }
            } else {
                // gather fallback (window too wide for LDS) — R11-proven
                const __half2 wy0h = __builtin_bit_cast(__half2, V.z);
                const __half2 wy1h = __builtin_bit_cast(__half2, V.w);
                const uint4* r0p0 = (const uint4*)(xbase + (size_t)(V.x + ((unsigned)cx0 << 6)));
                const uint4* r0p1 = (const uint4*)(xbase + (size_t)(V.x + ((unsigned)cx1 << 6)));
                const uint4* r1p0 = (const uint4*)(xbase + (size_t)(V.y + ((unsigned)cx0 << 6)));
                const uint4* r1p1 = (const uint4*)(xbase + (size_t)(V.y + ((unsigned)cx1 << 6)));
#pragma unroll
                for (int i = 0; i < 4; ++i) {
                    const uint4 a  = r0p0[i];
                    const uint4 bq = r0p1[i];
                    const uint4 c2 = r1p0[i];
                    const uint4 d  = r1p1[i];
#pragma unroll
                    for (int w = 0; w < 4; ++w) {
                        __half2 top = __hmul2(__builtin_bit_cast(__half2, (&a.x)[w]), wx0);
                        top = __hfma2(__builtin_bit_cast(__half2, (&bq.x)[w]), wx1, top);
                        __half2 bot = __hmul2(__builtin_bit_cast(__half2, (&c2.x)[w]), wx0);
                        bot = __hfma2(__builtin_bit_cast(__half2, (&d.x)[w]), wx1, bot);
                        __half2 v = __hmul2(top, wy0h);
                        v = __hfma2(bot, wy1h, v);
                        acc = fdot2_acc(v, yh[i * 4 + w], acc);
                    }
                }
            }

            // ---- STAGE step s+1 (write-late) ----
            // WAR vs consume(s) above is safe: one wave's DS ops execute in
            // order, and the compiler can't reorder may-aliasing LDS ops.
            if (s + 1 < SS) {
                if (tn == 0) {
                    const __half2 wy0h = __builtin_bit_cast(__half2, Vn.z);
                    const __half2 wy1h = __builtin_bit_cast(__half2, Vn.w);
#pragma unroll
                    for (int i = 0; i < PW; ++i) {
                        const int c = lane + i * 64;
                        if (c < width4n) {
                            uint4 o;
#pragma unroll
                            for (int q = 0; q < 4; ++q) {
                                __half2 r = __hmul2(__builtin_bit_cast(__half2, (&pa[i].x)[q]), wy0h);
                                r = __hfma2(__builtin_bit_cast(__half2, (&pb[i].x)[q]), wy1h, r);
                                (&o.x)[q] = __builtin_bit_cast(unsigned, r);
                            }
                            comb[c & 3][c >> 2] = o;
                        }
                    }
                    __syncthreads();   // stage(s+1) visible before consume(s+1)
                } else if (tn == 1) {
                    const __half2 wy0h = __builtin_bit_cast(__half2, Vn.z);
                    const __half2 wy1h = __builtin_bit_cast(__half2, Vn.w);
                    for (int c = lane; c < width4n; c += 64) {
                        const int cpx = min(max(xlon + (c >> 2), 0), WW - 1);
                        const unsigned po = (unsigned)((cpx << 6) + ((c & 3) << 4));
                        const uint4 a  = *(const uint4*)(xbase + (size_t)(Vn.x + po));
                        const uint4 bq = *(const uint4*)(xbase + (size_t)(Vn.y + po));
                        uint4 o;
#pragma unroll
                        for (int q = 0; q < 4; ++q) {
                            __half2 r = __hmul2(__builtin_bit_cast(__half2, (&a.x)[q]), wy0h);
                            r = __hfma2(__builtin_bit_cast(__half2, (&bq.x)[q]), wy1h, r);
                            (&o.x)[q] = __builtin_bit_cast(unsigned, r);
                        }
                        comb[c & 3][c >> 2] = o;
                    }
                    __syncthreads();
                }
                // tn==2: step s+1 gathers from global; no staging, no barrier.
                U = Un;
                V = Vn;
            }

            res[j] = acc * (1.0f / 32.0f);
        }
        // 32B sector-aligned store per 8-step group.
        *(float4*)(outp + g * 8)     = make_float4(res[0], res[1], res[2], res[3]);
        *(float4*)(outp + g * 8 + 4) = make_float4(res[4], res[5], res[6], res[7]);
    }
}

extern "C" void kernel_launch(void* const* d_in, const int* in_sizes, int n_in,
                              void* d_out, int out_size, void* d_ws, size_t ws_size,
                              hipStream_t stream) {
    const float* x = (const float*)d_in[0];
    const float* y = (const float*)d_in[1];
    const float* origin = (const float*)d_in[2];
    const float* focal = (const float*)d_in[3];
    const float* T12 = (const float*)d_in[4];
    float* out = (float*)d_out;
    __half* xh = (__half*)d_ws;   // needs BB*HH*WW*CC*2 = 31.5 MB

    const int nelem = BB * HH * WW * CC;          // 15,728,640
    convert_x_kernel<<<nelem / (256 * 8), 256, 0, stream>>>(x, xh);

    corr_kernel<<<NWG, 64, 0, stream>>>(xh, y, origin, focal, T12, out);
}